// Round 5
// baseline (2025.469 us; speedup 1.0000x reference)
//
#include <hip/hip_runtime.h>

#define NN 50000
#define NE 400000
#define DD 128
#define HH 4
#define DHH 32
#define TT 3
#define RR 6
#define LL 2
#define EPSF 1e-5f

typedef unsigned short ushort_t;
typedef unsigned int uint_t;

__device__ inline ushort_t f2bf(float f){
  union { float f; uint_t u; } x; x.f = f;
  uint_t r = x.u + 0x7fffu + ((x.u >> 16) & 1u);
  return (ushort_t)(r >> 16);
}
__device__ inline float bf2f(ushort_t u){
  union { uint_t u; float f; } x; x.u = ((uint_t)u) << 16;
  return x.f;
}

// ---------------- CSR build ----------------
__global__ void hist_kernel(const int* __restrict__ dst, int* __restrict__ cnt){
  int e = blockIdx.x*256 + threadIdx.x;
  if (e < NE) atomicAdd(&cnt[dst[e]], 1);
}

__global__ void scan_kernel(const int* __restrict__ deg, int* __restrict__ rowptr){
  __shared__ int wsum[16];
  __shared__ int carrySh;
  int tid = threadIdx.x, lane = tid & 63, w = tid >> 6;
  if (tid == 0){ carrySh = 0; rowptr[0] = 0; }
  __syncthreads();
  for (int base = 0; base < NN; base += 1024){
    int i = base + tid;
    int v = (i < NN) ? deg[i] : 0;
    int s = v;
    #pragma unroll
    for (int off=1; off<64; off<<=1){ int t = __shfl_up(s, off); if (lane >= off) s += t; }
    if (lane == 63) wsum[w] = s;
    __syncthreads();
    if (w == 0 && lane < 16){
      int t = wsum[lane];
      #pragma unroll
      for (int off=1; off<16; off<<=1){ int u = __shfl_up(t, off); if (lane >= off) t += u; }
      wsum[lane] = t;
    }
    __syncthreads();
    int waveOff = (w == 0) ? 0 : wsum[w-1];
    int incl = s + waveOff + carrySh;
    if (i < NN) rowptr[i+1] = incl;
    __syncthreads();
    if (tid == 0) carrySh += wsum[15];
    __syncthreads();
  }
}

// scatter: packed (src | etype<<27) in CSR order
__global__ void scatter_kernel(const int* __restrict__ dst, const int* __restrict__ src,
                               const int* __restrict__ etype, const int* __restrict__ rowptr,
                               int* __restrict__ cnt, uint_t* __restrict__ sr){
  int e = blockIdx.x*256 + threadIdx.x;
  if (e < NE){
    int d = dst[e];
    int pos = rowptr[d] + atomicAdd(&cnt[d], 1);
    sr[pos] = (uint_t)src[e] | ((uint_t)etype[e] << 27);
  }
}

// ---------------- typed K/Q/V GEMM + fused qhat (all relations) ----------------
// outputs: kv packed bf16 pair; qhat[n][r][c] fp32 (q itself never materialized)
__global__ __launch_bounds__(256) void kqv_kernel(
    const float* __restrict__ x, const int* __restrict__ ntype,
    const float* __restrict__ Wk, const float* __restrict__ Wq, const float* __restrict__ Wv,
    const float* __restrict__ Watt,
    uint_t* __restrict__ kvout, float* __restrict__ qhat)
{
  __shared__ float xs[16][DD];
  __shared__ int nts[16];
  int tid = threadIdx.x;
  int n0 = blockIdx.x * 16;
  #pragma unroll
  for (int it=0; it<8; it++){
    int i = tid + it*256;
    xs[i>>7][i&127] = x[(size_t)n0*DD + i];
  }
  if (tid < 16) nts[tid] = ntype[n0 + tid];
  __syncthreads();
  int c = tid & 127, nb = (tid >> 7) * 8;
  float ak[8], aq[8], av[8];
  #pragma unroll
  for (int j=0;j<8;j++){ ak[j]=0.f; aq[j]=0.f; av[j]=0.f; }
  int t0 = nts[nb];
  bool uni = true;
  #pragma unroll
  for (int j=1;j<8;j++) uni = uni && (nts[nb+j] == t0);
  if (uni){
    const float* wk = Wk + (size_t)t0*DD*DD + c;
    const float* wq = Wq + (size_t)t0*DD*DD + c;
    const float* wv = Wv + (size_t)t0*DD*DD + c;
    for (int d=0; d<DD; d+=4){
      float k0=wk[(d+0)*DD], k1=wk[(d+1)*DD], k2=wk[(d+2)*DD], k3=wk[(d+3)*DD];
      float q0=wq[(d+0)*DD], q1=wq[(d+1)*DD], q2=wq[(d+2)*DD], q3=wq[(d+3)*DD];
      float v0=wv[(d+0)*DD], v1=wv[(d+1)*DD], v2=wv[(d+2)*DD], v3=wv[(d+3)*DD];
      #pragma unroll
      for (int j=0;j<8;j++){
        float4 xv = *(const float4*)&xs[nb+j][d];
        ak[j] += xv.x*k0 + xv.y*k1 + xv.z*k2 + xv.w*k3;
        aq[j] += xv.x*q0 + xv.y*q1 + xv.z*q2 + xv.w*q3;
        av[j] += xv.x*v0 + xv.y*v1 + xv.z*v2 + xv.w*v3;
      }
    }
  } else {
    #pragma unroll
    for (int j=0;j<8;j++){
      int t = nts[nb+j];
      const float* wk = Wk + (size_t)t*DD*DD + c;
      const float* wq = Wq + (size_t)t*DD*DD + c;
      const float* wv = Wv + (size_t)t*DD*DD + c;
      float sk=0.f, sq=0.f, sv=0.f;
      for (int d=0; d<DD; d+=4){
        float4 xv = *(const float4*)&xs[nb+j][d];
        sk += xv.x*wk[d*DD] + xv.y*wk[(d+1)*DD] + xv.z*wk[(d+2)*DD] + xv.w*wk[(d+3)*DD];
        sq += xv.x*wq[d*DD] + xv.y*wq[(d+1)*DD] + xv.z*wq[(d+2)*DD] + xv.w*wq[(d+3)*DD];
        sv += xv.x*wv[d*DD] + xv.y*wv[(d+1)*DD] + xv.z*wv[(d+2)*DD] + xv.w*wv[(d+3)*DD];
      }
      ak[j]=sk; aq[j]=sq; av[j]=sv;
    }
  }
  #pragma unroll
  for (int j=0;j<8;j++){
    size_t row = (size_t)(n0 + nb + j)*DD + c;
    kvout[row] = (uint_t)f2bf(ak[j]) | ((uint_t)f2bf(av[j]) << 16);
  }
  // ---- qhat stage: reuse xs to hold q-tile ----
  __syncthreads();
  #pragma unroll
  for (int j=0;j<8;j++) xs[nb+j][c] = aq[j];
  __syncthreads();
  int h = c >> 5, dd = c & 31;
  #pragma unroll
  for (int r=0;r<RR;r++){
    // qhat[n][r][c] = sum_cc Watt[h][r][dd][cc] * q[n][h*32+cc]
    const float4* w4 = (const float4*)(Watt + (((h*RR + r) << 10) + (dd << 5)));
    float s[8];
    #pragma unroll
    for (int j=0;j<8;j++) s[j]=0.f;
    #pragma unroll
    for (int i4=0; i4<8; i4++){
      float4 w = w4[i4];
      #pragma unroll
      for (int j=0;j<8;j++){
        float4 qv = *(const float4*)&xs[nb+j][(h<<5) + i4*4];
        s[j] += w.x*qv.x + w.y*qv.y + w.z*qv.z + w.w*qv.w;
      }
    }
    #pragma unroll
    for (int j=0;j<8;j++)
      qhat[((size_t)(n0 + nb + j)*RR + r)*DD + c] = s[j];
  }
}

// ---------------- slim fused edge pipeline ----------------
// per node: gather kv + L1-hot qhat rows; batched online softmax; 6 relation
// accumulators in v-space; stores normalized sacc (bf16) aliased into qhat region.
// NOTE: qhat/sacc intentionally alias (per-node reads all precede writes) — no __restrict__.
__global__ __launch_bounds__(128) void edge_kernel(
    const uint_t* __restrict__ kvb, const float* qhat,
    const int* __restrict__ rowptr, const uint_t* __restrict__ src_r,
    const float* __restrict__ pri, ushort_t* sacc)
{
  int n = blockIdx.x;
  int tid = threadIdx.x;          // 128 = H*DH
  int h = tid >> 5;
  __shared__ float psh[HH*RR];
  if (tid < HH*RR) psh[tid] = pri[tid] * 0.17677669529663687f;
  __syncthreads();
  const float* qbase = qhat + (size_t)n*RR*DD;
  int b = rowptr[n], e1 = rowptr[n+1];
  float a0=0.f,a1=0.f,a2=0.f,a3=0.f,a4=0.f,a5=0.f;
  float den = 0.f, m = -1e30f;
  for (int i=b; i<e1; i+=8){
    int m8 = e1 - i; if (m8 > 8) m8 = 8;
    uint_t sr[8];
    #pragma unroll
    for (int jj=0;jj<8;jj++) sr[jj] = src_r[i + ((jj < m8) ? jj : (m8-1))];
    uint_t kv[8]; float qv[8];
    #pragma unroll
    for (int jj=0;jj<8;jj++){
      kv[jj] = kvb[(size_t)(sr[jj] & 0x07FFFFFFu)*DD + tid];
      qv[jj] = qbase[((sr[jj] >> 27) << 7) + tid];
    }
    float aa[8];
    #pragma unroll
    for (int jj=0;jj<8;jj++){
      float kf = bf2f((ushort_t)(kv[jj] & 0xffffu));
      float p = kf * qv[jj];
      #pragma unroll
      for (int off=16; off>0; off>>=1) p += __shfl_xor(p, off);
      int r = (int)(sr[jj] >> 27);
      aa[jj] = (jj < m8) ? p * psh[h*RR + r] : -1e30f;
    }
    float mb = aa[0];
    #pragma unroll
    for (int jj=1;jj<8;jj++) mb = fmaxf(mb, aa[jj]);
    float mnew = fmaxf(m, mb);
    float corr = __expf(m - mnew);
    m = mnew;
    den *= corr; a0*=corr; a1*=corr; a2*=corr; a3*=corr; a4*=corr; a5*=corr;
    #pragma unroll
    for (int jj=0;jj<8;jj++){
      float ex = __expf(aa[jj] - mnew);
      den += ex;
      float vf = bf2f((ushort_t)(kv[jj] >> 16));
      float exv = ex * vf;
      int r = (int)(sr[jj] >> 27);
      a0 += (r==0)? exv : 0.f;
      a1 += (r==1)? exv : 0.f;
      a2 += (r==2)? exv : 0.f;
      a3 += (r==3)? exv : 0.f;
      a4 += (r==4)? exv : 0.f;
      a5 += (r==5)? exv : 0.f;
    }
  }
  float inv = (den > 0.f) ? 1.f/den : 0.f;
  ushort_t* sb = sacc + (size_t)n*(RR*DD*2);   // node stride matches qhat (3072B)
  sb[(0<<7)+tid] = f2bf(a0*inv);
  sb[(1<<7)+tid] = f2bf(a1*inv);
  sb[(2<<7)+tid] = f2bf(a2*inv);
  sb[(3<<7)+tid] = f2bf(a3*inv);
  sb[(4<<7)+tid] = f2bf(a4*inv);
  sb[(5<<7)+tid] = f2bf(a5*inv);
}

// ---------------- W_msg apply + typed output GEMM + skip gate ----------------
__global__ __launch_bounds__(256) void ha_kernel(
    const ushort_t* __restrict__ sacc, const float* __restrict__ x, const int* __restrict__ ntype,
    const float* __restrict__ Wmsg, const float* __restrict__ Wa, const float* __restrict__ skipl,
    float* __restrict__ ho)
{
  __shared__ ushort_t ss[16*RR*DD];   // 16 nodes x 768 = 24KB
  __shared__ float xs[16][DD];
  __shared__ int nts[16];
  int tid = threadIdx.x;
  int n0 = blockIdx.x * 16;
  // stage sacc tile (global node stride = 1536 ushorts; 768 used)
  #pragma unroll
  for (int it=0; it<12; it++){
    int c4 = tid + it*256;            // 3072 chunks of 4 ushorts
    int j = c4 / 192;
    int k = (c4 - j*192) * 4;
    *(uint2*)&ss[j*768 + k] = *(const uint2*)&sacc[(size_t)(n0+j)*1536 + k];
  }
  if (tid < 16) nts[tid] = ntype[n0 + tid];
  __syncthreads();
  int c = tid & 127, nb = (tid >> 7) * 8;
  int h = c >> 5, o = c & 31;
  // msg stage: agg[n][c] = sum_r sum_d Wmsg[h][r][d][o] * sacc[n][r][h*32+d]
  float agg8[8];
  #pragma unroll
  for (int j=0;j<8;j++) agg8[j]=0.f;
  #pragma unroll
  for (int r=0;r<RR;r++){
    const float* wm = Wmsg + ((h*RR + r) << 10) + o;
    const ushort_t* s0 = ss + r*DD + (h<<5);
    #pragma unroll 8
    for (int d=0; d<DHH; d++){
      float w = wm[d << 5];
      #pragma unroll
      for (int j=0;j<8;j++)
        agg8[j] += w * bf2f(s0[(nb+j)*768 + d]);
    }
  }
  #pragma unroll
  for (int j=0;j<8;j++) xs[nb+j][c] = agg8[j];
  __syncthreads();
  // typed Wa GEMM
  float acc[8];
  #pragma unroll
  for (int j=0;j<8;j++) acc[j]=0.f;
  int t0 = nts[nb];
  bool uni = true;
  #pragma unroll
  for (int j=1;j<8;j++) uni = uni && (nts[nb+j] == t0);
  if (uni){
    const float* wa = Wa + (size_t)t0*DD*DD + c;
    for (int d=0; d<DD; d+=4){
      float w0=wa[(d+0)*DD], w1=wa[(d+1)*DD], w2=wa[(d+2)*DD], w3=wa[(d+3)*DD];
      #pragma unroll
      for (int j=0;j<8;j++){
        float4 xv = *(const float4*)&xs[nb+j][d];
        acc[j] += xv.x*w0 + xv.y*w1 + xv.z*w2 + xv.w*w3;
      }
    }
  } else {
    #pragma unroll
    for (int j=0;j<8;j++){
      int t = nts[nb+j];
      const float* wa = Wa + (size_t)t*DD*DD + c;
      float sacc2 = 0.f;
      for (int d=0; d<DD; d+=4){
        float4 xv = *(const float4*)&xs[nb+j][d];
        sacc2 += xv.x*wa[d*DD] + xv.y*wa[(d+1)*DD] + xv.z*wa[(d+2)*DD] + xv.w*wa[(d+3)*DD];
      }
      acc[j] = sacc2;
    }
  }
  #pragma unroll
  for (int j=0;j<8;j++){
    int n = n0 + nb + j;
    float sk = 1.f/(1.f + __expf(-skipl[nts[nb+j]]));
    size_t row = (size_t)n*DD + c;
    ho[row] = acc[j]*sk + x[row]*(1.f - sk);
  }
}

// ---------------- LayerNorm(x + ho) ----------------
__global__ __launch_bounds__(256) void ln_kernel(
    const float* __restrict__ x, const float* __restrict__ ho,
    const float* __restrict__ g, const float* __restrict__ b,
    float* __restrict__ xout)
{
  int lane = threadIdx.x & 63;
  int n = blockIdx.x*4 + (threadIdx.x >> 6);
  size_t base = (size_t)n*DD;
  float t0 = x[base+lane]    + ho[base+lane];
  float t1 = x[base+lane+64] + ho[base+lane+64];
  float s = t0 + t1;
  #pragma unroll
  for (int off=32; off>0; off>>=1) s += __shfl_xor(s, off);
  float mu = s * (1.f/DD);
  float d0 = t0-mu, d1 = t1-mu;
  float vs = d0*d0 + d1*d1;
  #pragma unroll
  for (int off=32; off>0; off>>=1) vs += __shfl_xor(vs, off);
  float inv = rsqrtf(vs*(1.f/DD) + EPSF);
  xout[base+lane]    = d0*inv*g[lane]    + b[lane];
  xout[base+lane+64] = d1*inv*g[lane+64] + b[lane+64];
}

// ---------------- final mix + LayerNorm ----------------
__global__ __launch_bounds__(256) void final_kernel(
    const float* __restrict__ x1, const float* __restrict__ x2,
    const float* __restrict__ aggw, const float* __restrict__ g, const float* __restrict__ b,
    float* __restrict__ out)
{
  int lane = threadIdx.x & 63;
  int n = blockIdx.x*4 + (threadIdx.x >> 6);
  float a0 = aggw[0], a1 = aggw[1];
  float m = fmaxf(a0, a1);
  float e0 = __expf(a0-m), e1 = __expf(a1-m);
  float inv01 = 1.f/(e0+e1);
  float w0 = e0*inv01, w1 = e1*inv01;
  size_t base = (size_t)n*DD;
  float t0 = w0*x1[base+lane]    + w1*x2[base+lane];
  float t1 = w0*x1[base+lane+64] + w1*x2[base+lane+64];
  float s = t0 + t1;
  #pragma unroll
  for (int off=32; off>0; off>>=1) s += __shfl_xor(s, off);
  float mu = s * (1.f/DD);
  float d0 = t0-mu, d1 = t1-mu;
  float vs = d0*d0 + d1*d1;
  #pragma unroll
  for (int off=32; off>0; off>>=1) vs += __shfl_xor(vs, off);
  float invv = rsqrtf(vs*(1.f/DD) + EPSF);
  out[base+lane]    = d0*invv*g[lane]    + b[lane];
  out[base+lane+64] = d1*invv*g[lane+64] + b[lane+64];
}

extern "C" void kernel_launch(void* const* d_in, const int* in_sizes, int n_in,
                              void* d_out, int out_size, void* d_ws, size_t ws_size,
                              hipStream_t stream)
{
  (void)in_sizes; (void)n_in; (void)out_size; (void)ws_size;
  const float* h_in  = (const float*)d_in[0];
  const int*   src   = (const int*)d_in[1];
  const int*   dst   = (const int*)d_in[2];
  const int*   ntype = (const int*)d_in[3];
  const int*   etype = (const int*)d_in[4];
  const float* Wk    = (const float*)d_in[5];
  const float* Wq    = (const float*)d_in[6];
  const float* Wv    = (const float*)d_in[7];
  const float* Wa    = (const float*)d_in[8];
  const float* Watt  = (const float*)d_in[9];
  const float* Wmsg  = (const float*)d_in[10];
  const float* pri   = (const float*)d_in[11];
  const float* skp   = (const float*)d_in[12];
  const float* lng   = (const float*)d_in[13];
  const float* lnb   = (const float*)d_in[14];
  const float* aggw  = (const float*)d_in[15];
  const float* aggg  = (const float*)d_in[16];
  const float* aggb_ = (const float*)d_in[17];

  size_t P = (size_t)NN*DD;
  uint_t* kvbuf = (uint_t*)d_ws;                 // P packed (k,v) bf16
  float* qhat  = (float*)(kvbuf + P);            // N*R*D f32 (sacc bf16 aliases this region)
  float* hob   = qhat + (size_t)NN*RR*DD;        // P f32
  float* out0  = hob + P;                        // P f32 (layer-0 output)
  int* rowptr = (int*)(out0 + P);
  int* cnt    = rowptr + NN + 1;
  uint_t* srcr = (uint_t*)(cnt + NN);            // NE packed (src | etype<<27)
  float* xout = (float*)d_out;

  // CSR by dst
  hipMemsetAsync(cnt, 0, NN*sizeof(int), stream);
  hist_kernel<<<(NE+255)/256, 256, 0, stream>>>(dst, cnt);
  scan_kernel<<<1, 1024, 0, stream>>>(cnt, rowptr);
  hipMemsetAsync(cnt, 0, NN*sizeof(int), stream);
  scatter_kernel<<<(NE+255)/256, 256, 0, stream>>>(dst, src, etype, rowptr, cnt, srcr);

  const float* x = h_in;
  for (int l=0; l<LL; l++){
    const float* Wk_l  = Wk  + (size_t)l*TT*DD*DD;
    const float* Wq_l  = Wq  + (size_t)l*TT*DD*DD;
    const float* Wv_l  = Wv  + (size_t)l*TT*DD*DD;
    const float* Wa_l  = Wa  + (size_t)l*TT*DD*DD;
    const float* Wat_l = Watt + (size_t)l*HH*RR*DHH*DHH;
    const float* Wms_l = Wmsg + (size_t)l*HH*RR*DHH*DHH;
    const float* pri_l = pri + (size_t)l*HH*RR;
    const float* skp_l = skp + (size_t)l*TT;

    kqv_kernel<<<NN/16, 256, 0, stream>>>(x, ntype, Wk_l, Wq_l, Wv_l, Wat_l, kvbuf, qhat);
    edge_kernel<<<NN, 128, 0, stream>>>(kvbuf, qhat, rowptr, srcr, pri_l, (ushort_t*)qhat);
    ha_kernel<<<NN/16, 256, 0, stream>>>((const ushort_t*)qhat, x, ntype, Wms_l, Wa_l, skp_l, hob);
    float* xo = (l == 0) ? out0 : xout;
    ln_kernel<<<NN/4, 256, 0, stream>>>(x, hob, lng + (size_t)l*DD, lnb + (size_t)l*DD, xo);
    x = xo;
  }
  final_kernel<<<NN/4, 256, 0, stream>>>(out0, xout, aggw, aggg, aggb_, xout);
}